// Round 3
// baseline (10952.074 us; speedup 1.0000x reference)
//
#include <hip/hip_runtime.h>

using u16 = unsigned short;
typedef short bf16x8 __attribute__((ext_vector_type(8)));
typedef float f32x4 __attribute__((ext_vector_type(4)));

// ---------------- workspace layout (bytes) ----------------
static constexpr size_t OFF_W1  = 0;                              // 4096x1536 bf16 [Wih1|Whh1]
static constexpr size_t OFF_W2  = OFF_W1 + (size_t)4096*1536*2;   // 4096x2048 bf16 [Wih2|Whh2]
static constexpr size_t OFF_W3  = OFF_W2 + (size_t)4096*2048*2;
static constexpr size_t OFF_W4  = OFF_W3 + (size_t)4096*2048*2;
static constexpr size_t OFF_BS  = OFF_W4 + (size_t)4096*2048*2;   // 4*4096 f32 (bih+bhh)
static constexpr size_t OFF_XB  = OFF_BS + (size_t)4*4096*4;      // 256*64*512 bf16 time-major
static constexpr size_t OFF_H   = OFF_XB + (size_t)256*64*512*2;  // 4 cells * 2 bufs * 64*1024 bf16
static constexpr size_t OFF_C   = OFF_H  + (size_t)4*2*65536*2;   // 4 * 64*1024 f32
static constexpr size_t OFF_BAR = OFF_C  + (size_t)4*65536*4;     // barrier counters
static constexpr size_t WS_TOTAL= OFF_BAR + 4096;

__device__ __forceinline__ u16 f2b(float f) {               // f32 -> bf16 bits, RNE
  union { float f; unsigned u; } a; a.f = f;
  unsigned r = a.u + 0x7fffu + ((a.u >> 16) & 1u);
  return (u16)(r >> 16);
}

// ---------------- prep kernels ----------------
__global__ void k_prep_cell(const float* __restrict__ Wih, const float* __restrict__ Whh,
                            int Kih, int Khh, u16* __restrict__ Wcat)
{
  const int r = blockIdx.y;
  const int k = blockIdx.x * blockDim.x + threadIdx.x;
  const int K = Kih + Khh;
  float v = (k < Kih) ? Wih[(size_t)r * Kih + k] : Whh[(size_t)r * Khh + (k - Kih)];
  Wcat[(size_t)r * K + k] = f2b(v);
}

__global__ void k_bsum(const float* b1i, const float* b1h, const float* b2i, const float* b2h,
                       const float* b3i, const float* b3h, const float* b4i, const float* b4h,
                       float* __restrict__ bs)
{
  const int i = blockIdx.x * blockDim.x + threadIdx.x;   // 0..16383
  const int n = i >> 12, j = i & 4095;
  const float* bi = (n == 0) ? b1i : (n == 1) ? b2i : (n == 2) ? b3i : b4i;
  const float* bh = (n == 0) ? b1h : (n == 1) ? b2h : (n == 2) ? b3h : b4h;
  bs[i] = bi[j] + bh[j];
}

__global__ void k_xconv(const float* __restrict__ x, u16* __restrict__ xb)
{
  const int blk = blockIdx.x;            // t*64 + b
  const int t = blk >> 6, b = blk & 63;
  const int i = threadIdx.x * 4;         // 128 thr * 4 elems = 512
  const float4 v = *(const float4*)(x + ((size_t)b * 256 + t) * 512 + i);
  ushort4 s;
  s.x = f2b(v.x); s.y = f2b(v.y); s.z = f2b(v.z); s.w = f2b(v.w);
  *(ushort4*)(xb + (size_t)blk * 512 + i) = s;
}

__global__ void k_zero(uint4* __restrict__ p, int n16)
{
  const int i = blockIdx.x * blockDim.x + threadIdx.x;
  if (i < n16) { uint4 z; z.x = z.y = z.z = z.w = 0u; p[i] = z; }
}

// ---------------- grid barrier (2-level, agent scope) ----------------
__device__ __forceinline__ void grid_barrier(unsigned* bar, unsigned gen)
{
  __syncthreads();
  if (threadIdx.x == 0) {
    unsigned* gcnt = bar + ((blockIdx.x & 7) << 5);   // 8 counters, 128B apart
    unsigned* root = bar + 256;
    unsigned* rel  = bar + 288;
    const unsigned p = __hip_atomic_fetch_add(gcnt, 1u, __ATOMIC_ACQ_REL, __HIP_MEMORY_SCOPE_AGENT);
    if (p == gen * 16u + 15u) {                       // last of this group of 16
      const unsigned q = __hip_atomic_fetch_add(root, 1u, __ATOMIC_ACQ_REL, __HIP_MEMORY_SCOPE_AGENT);
      if (q == gen * 8u + 7u)
        __hip_atomic_store(rel, gen + 1u, __ATOMIC_RELEASE, __HIP_MEMORY_SCOPE_AGENT);
    }
    while (__hip_atomic_load(rel, __ATOMIC_ACQUIRE, __HIP_MEMORY_SCOPE_AGENT) < gen + 1u)
      __builtin_amdgcn_s_sleep(2);
  }
  __syncthreads();
}

// ---------------- one cell phase ----------------
// WG covers batch rows [rh*32, rh*32+32) x output cols [cg*16, cg*16+16) x all 4 gates.
// wave wv computes gate wv. A (inputs) staged to LDS in 512-K sections, XOR-swizzled.
template<int NSEC>
__device__ __forceinline__ void run_cell(
    char* A_lds, float (*gl)[32][17],
    const u16* const (&src)[NSEC], const int (&sstr)[NSEC], const int (&soff)[NSEC],
    const u16* __restrict__ Wc, const int Kw,
    const float* __restrict__ bsum, float* __restrict__ cst,
    u16* __restrict__ hnext, float* __restrict__ outp,
    const int rh, const int cg)
{
  const int tid  = threadIdx.x;
  const int lane = tid & 63;
  const int wv   = tid >> 6;          // wave = gate (0:i 1:f 2:g 3:o)
  const int l15  = lane & 15;
  const int l4   = lane >> 4;
  const int xr   = (l15 & 7) << 4;    // LDS XOR swizzle slot

  f32x4 acc0 = {0.f, 0.f, 0.f, 0.f};
  f32x4 acc1 = {0.f, 0.f, 0.f, 0.f};

  const size_t wrow = (size_t)((wv << 10) + (cg << 4) + l15) * (size_t)Kw + (l4 << 3);

  uint4 wA[16], wB[16];
  {
    const u16* wr = Wc + wrow;        // section 0 weights
    #pragma unroll
    for (int k0 = 0; k0 < 16; ++k0) wA[k0] = *(const uint4*)(wr + (k0 << 5));
  }

  #pragma unroll
  for (int s = 0; s < NSEC; ++s) {
    __syncthreads();
    {   // stage A section s: 32 rows x 512 k bf16 -> LDS (swizzled)
      const u16* S = src[s];
      const int st = sstr[s];
      const int so = soff[s];
      #pragma unroll
      for (int i = 0; i < 8; ++i) {
        const int ch = tid + (i << 8);            // 0..2047 chunks of 16B
        const int lr = ch >> 6;                   // local row 0..31
        const int kc = (ch & 63) << 3;            // k elem 0..504
        const uint4 v = *(const uint4*)(S + (size_t)(rh * 32 + lr) * st + so + kc);
        *(uint4*)(A_lds + lr * 1024 + ((kc * 2) ^ ((lr & 7) << 4))) = v;
      }
    }
    if (s + 1 < NSEC) {               // prefetch next section's W (ping-pong)
      const u16* wr = Wc + wrow + ((s + 1) << 9);
      if ((s & 1) == 0) {
        #pragma unroll
        for (int k0 = 0; k0 < 16; ++k0) wB[k0] = *(const uint4*)(wr + (k0 << 5));
      } else {
        #pragma unroll
        for (int k0 = 0; k0 < 16; ++k0) wA[k0] = *(const uint4*)(wr + (k0 << 5));
      }
    }
    __syncthreads();
    const uint4* wc = ((s & 1) == 0) ? wA : wB;
    #pragma unroll
    for (int k0 = 0; k0 < 16; ++k0) {
      const int kb = (k0 << 6) + (l4 << 4);
      bf16x8 a0 = *(const bf16x8*)(A_lds + (l15 << 10) + (kb ^ xr));
      bf16x8 a1 = *(const bf16x8*)(A_lds + ((16 + l15) << 10) + (kb ^ xr));
      bf16x8 b  = __builtin_bit_cast(bf16x8, wc[k0]);
      acc0 = __builtin_amdgcn_mfma_f32_16x16x32_bf16(a0, b, acc0, 0, 0, 0);
      acc1 = __builtin_amdgcn_mfma_f32_16x16x32_bf16(a1, b, acc1, 0, 0, 0);
    }
  }

  __syncthreads();
  // D layout (m89-verified): elem r -> (m = 4*(l>>4)+r, n = l&15)
  #pragma unroll
  for (int r = 0; r < 4; ++r) {
    gl[wv][(l4 << 2) + r][l15]      = acc0[r];
    gl[wv][16 + (l4 << 2) + r][l15] = acc1[r];
  }
  __syncthreads();

  for (int e = tid; e < 512; e += 256) {
    const int lr = e >> 4, lc = e & 15;
    const int col  = (cg << 4) + lc;
    const int brow = rh * 32 + lr;
    const float gi = gl[0][lr][lc] + bsum[col];
    const float gf = gl[1][lr][lc] + bsum[1024 + col];
    const float gg = gl[2][lr][lc] + bsum[2048 + col];
    const float go = gl[3][lr][lc] + bsum[3072 + col];
    const float ii = 1.f / (1.f + __expf(-gi));
    const float ff = 1.f / (1.f + __expf(-gf));
    const float gc = tanhf(gg);
    const float oo = 1.f / (1.f + __expf(-go));
    const int idx = (brow << 10) + col;
    const float cn = ff * cst[idx] + ii * gc;
    cst[idx] = cn;
    const float hn = oo * tanhf(cn);
    hnext[idx] = f2b(hn);
    if (outp) outp[idx] = hn;
  }
}

// ---------------- persistent MTRNN kernel ----------------
__global__ void __launch_bounds__(256) k_mtrnn(char* __restrict__ ws, float* __restrict__ out)
{
  __shared__ alignas(16) char A_lds[32768];
  __shared__ float gl[4][32][17];

  const int bid = blockIdx.x;
  const int rh  = bid & 1;     // batch-row half
  const int cg  = bid >> 1;    // column group (16 cols)

  const u16* W1 = (const u16*)(ws + OFF_W1);
  const u16* W2 = (const u16*)(ws + OFF_W2);
  const u16* W3 = (const u16*)(ws + OFF_W3);
  const u16* W4 = (const u16*)(ws + OFF_W4);
  const float* bs = (const float*)(ws + OFF_BS);
  const u16* xb = (const u16*)(ws + OFF_XB);
  u16* hb       = (u16*)(ws + OFF_H);
  float* cs     = (float*)(ws + OFF_C);
  unsigned* bar = (unsigned*)(ws + OFF_BAR);

  #define HBUF(n, p) (hb + (((n) * 2 + (p)) << 16))

  unsigned gen = 0;
  int c1 = 0, c2 = 0, c3 = 0, c4 = 0;

  #pragma unroll 1
  for (int t = 0; t < 256; ++t) {
    {   // cell1: A = [x_t (512) ; h1 (1024)], K = 1536
      const u16* xt = xb + (size_t)t * 32768;
      const u16* h1 = HBUF(0, c1);
      const u16* src[3] = { xt, h1, h1 };
      const int sstr[3] = { 512, 1024, 1024 };
      const int soff[3] = { 0, 0, 512 };
      run_cell<3>(A_lds, gl, src, sstr, soff, W1, 1536, bs, cs,
                  HBUF(0, c1 ^ 1), nullptr, rh, cg);
      c1 ^= 1;
      grid_barrier(bar, gen); ++gen;
    }
    if ((t & 1) == 0) {   // cell2: A = [h1 ; h2], K = 2048
      const u16* hi = HBUF(0, c1);
      const u16* hs = HBUF(1, c2);
      const u16* src[4] = { hi, hi, hs, hs };
      const int sstr[4] = { 1024, 1024, 1024, 1024 };
      const int soff[4] = { 0, 512, 0, 512 };
      run_cell<4>(A_lds, gl, src, sstr, soff, W2, 2048, bs + 4096, cs + 65536,
                  HBUF(1, c2 ^ 1), nullptr, rh, cg);
      c2 ^= 1;
      grid_barrier(bar, gen); ++gen;
    }
    if ((t & 3) == 0) {   // cell3: A = [h2 ; h3]
      const u16* hi = HBUF(1, c2);
      const u16* hs = HBUF(2, c3);
      const u16* src[4] = { hi, hi, hs, hs };
      const int sstr[4] = { 1024, 1024, 1024, 1024 };
      const int soff[4] = { 0, 512, 0, 512 };
      run_cell<4>(A_lds, gl, src, sstr, soff, W3, 2048, bs + 8192, cs + 131072,
                  HBUF(2, c3 ^ 1), nullptr, rh, cg);
      c3 ^= 1;
      grid_barrier(bar, gen); ++gen;
    }
    if ((t & 7) == 0) {   // cell4: A = [h3 ; h4]; also writes f32 output
      const u16* hi = HBUF(2, c3);
      const u16* hs = HBUF(3, c4);
      const u16* src[4] = { hi, hi, hs, hs };
      const int sstr[4] = { 1024, 1024, 1024, 1024 };
      const int soff[4] = { 0, 512, 0, 512 };
      run_cell<4>(A_lds, gl, src, sstr, soff, W4, 2048, bs + 12288, cs + 196608,
                  HBUF(3, c4 ^ 1), out, rh, cg);
      c4 ^= 1;
      grid_barrier(bar, gen); ++gen;
    }
  }
  #undef HBUF
}

// ---------------- host ----------------
extern "C" void kernel_launch(void* const* d_in, const int* in_sizes, int n_in,
                              void* d_out, int out_size, void* d_ws, size_t ws_size,
                              hipStream_t stream)
{
  (void)in_sizes; (void)n_in; (void)out_size;
  if (ws_size < WS_TOTAL) return;   // workspace too small — fail loudly via wrong output

  const float* x = (const float*)d_in[0];
  const float* Wih[4] = { (const float*)d_in[1], (const float*)d_in[5],
                          (const float*)d_in[9], (const float*)d_in[13] };
  const float* Whh[4] = { (const float*)d_in[2], (const float*)d_in[6],
                          (const float*)d_in[10], (const float*)d_in[14] };
  const float* bih[4] = { (const float*)d_in[3], (const float*)d_in[7],
                          (const float*)d_in[11], (const float*)d_in[15] };
  const float* bhh[4] = { (const float*)d_in[4], (const float*)d_in[8],
                          (const float*)d_in[12], (const float*)d_in[16] };
  char* ws = (char*)d_ws;
  float* out = (float*)d_out;

  // weights -> concatenated bf16 [Wih|Whh] per cell
  k_prep_cell<<<dim3(6, 4096), 256, 0, stream>>>(Wih[0], Whh[0], 512, 1024, (u16*)(ws + OFF_W1));
  k_prep_cell<<<dim3(8, 4096), 256, 0, stream>>>(Wih[1], Whh[1], 1024, 1024, (u16*)(ws + OFF_W2));
  k_prep_cell<<<dim3(8, 4096), 256, 0, stream>>>(Wih[2], Whh[2], 1024, 1024, (u16*)(ws + OFF_W3));
  k_prep_cell<<<dim3(8, 4096), 256, 0, stream>>>(Wih[3], Whh[3], 1024, 1024, (u16*)(ws + OFF_W4));
  // bias sums
  k_bsum<<<64, 256, 0, stream>>>(bih[0], bhh[0], bih[1], bhh[1], bih[2], bhh[2], bih[3], bhh[3],
                                 (float*)(ws + OFF_BS));
  // x -> time-major bf16
  k_xconv<<<16384, 128, 0, stream>>>(x, (u16*)(ws + OFF_XB));
  // zero h (both buffers), c, barrier
  {
    const int n16 = (int)((WS_TOTAL - OFF_H) / 16);
    k_zero<<<(n16 + 255) / 256, 256, 0, stream>>>((uint4*)(ws + OFF_H), n16);
  }
  // persistent sequential kernel: 128 WGs (<= #CUs, co-resident), custom grid barrier
  k_mtrnn<<<128, 256, 0, stream>>>(ws, out);
}